// Round 1
// baseline (805.156 us; speedup 1.0000x reference)
//
#include <hip/hip_runtime.h>
#include <hip/hip_bf16.h>

#define BB 64
#define AA 8732
#define GG 50
#define CC 81
#define NEG_RATIO 3
#define NSORT 16384

// ws layout:
//   float acc_num            @ float offset 0
//   int   num_pos[BB]        @ float offset 64
//   float conf[BB*AA]        @ float offset 1024
//   float conf_neg[BB*AA]    @ float offset 1024 + BB*AA

__device__ __forceinline__ unsigned mono_key(float f) {
    unsigned u = __float_as_uint(f);
    u = (u & 0x80000000u) ? ~u : (u | 0x80000000u);  // ascending float -> ascending uint
    return ~u;                                        // ascending key == descending float
}

__global__ __launch_bounds__(256) void k_match(
    const float* __restrict__ pred_boxes, const float* __restrict__ pred_scores,
    const float* __restrict__ gt_boxes, const int* __restrict__ gt_labels,
    float* __restrict__ conf_out, float* __restrict__ confneg_out,
    int* __restrict__ num_pos, float* __restrict__ acc_num)
{
    __shared__ float4 sgt[GG];
    __shared__ int slab[GG];
    const int b = blockIdx.y;
    const int a = blockIdx.x * 256 + threadIdx.x;
    if (threadIdx.x < GG) {
        const float* gp = gt_boxes + ((size_t)b * GG + threadIdx.x) * 4;
        sgt[threadIdx.x] = make_float4(gp[0], gp[1], gp[2], gp[3]);
        slab[threadIdx.x] = gt_labels[b * GG + threadIdx.x];
    }
    __syncthreads();

    float contrib = 0.f;
    int ispos = 0;
    if (a < AA) {
        const size_t ai = (size_t)b * AA + a;
        const float4 pb = ((const float4*)pred_boxes)[ai];
        const float area_p = (pb.z - pb.x) * (pb.w - pb.y);
        float best = -1.f; int bidx = 0;
        #pragma unroll 5
        for (int g = 0; g < GG; ++g) {
            float4 gb = sgt[g];
            float iw = fmaxf(fminf(pb.z, gb.z) - fmaxf(pb.x, gb.x), 0.f);
            float ih = fmaxf(fminf(pb.w, gb.w) - fmaxf(pb.y, gb.y), 0.f);
            float inter = iw * ih;
            float area_g = (gb.z - gb.x) * (gb.w - gb.y);
            float uni = fmaxf(area_p + area_g - inter, 1e-6f);
            float iou = inter / uni;
            if (iou > best) { best = iou; bidx = g; }   // strict > keeps FIRST max (jnp.argmax)
        }
        const bool pos = best > 0.5f;
        const int label = pos ? slab[bidx] : 0;
        const bool pmask = label > 0;

        const float* sp = pred_scores + ai * CC;
        float mx = sp[0];
        for (int c = 1; c < CC; ++c) mx = fmaxf(mx, sp[c]);
        float s = 0.f;
        for (int c = 0; c < CC; ++c) s += __expf(sp[c] - mx);
        const float conf = mx + __logf(s) - sp[label];

        conf_out[ai] = conf;
        confneg_out[ai] = pmask ? -1.f : conf;

        if (pmask) {
            ispos = 1;
            float4 gb = sgt[bidx];
            float sl1 = 0.f, d, ad;
            d = pb.x - gb.x; ad = fabsf(d); sl1 += (ad < 1.f) ? 0.5f * d * d : ad - 0.5f;
            d = pb.y - gb.y; ad = fabsf(d); sl1 += (ad < 1.f) ? 0.5f * d * d : ad - 0.5f;
            d = pb.z - gb.z; ad = fabsf(d); sl1 += (ad < 1.f) ? 0.5f * d * d : ad - 0.5f;
            d = pb.w - gb.w; ad = fabsf(d); sl1 += (ad < 1.f) ? 0.5f * d * d : ad - 0.5f;
            contrib = sl1 + conf;   // loc_loss + conf_pos contributions
        }
    }

    // wave-64 reduce, one atomic per wave
    #pragma unroll
    for (int off = 32; off; off >>= 1) {
        contrib += __shfl_down(contrib, off);
        ispos   += __shfl_down(ispos, off);
    }
    if ((threadIdx.x & 63) == 0) {
        if (contrib != 0.f) atomicAdd(acc_num, contrib);
        if (ispos)          atomicAdd(&num_pos[b], ispos);
    }
}

__global__ __launch_bounds__(1024) void k_hardneg(
    const float* __restrict__ confneg, const float* __restrict__ conf,
    const int* __restrict__ num_pos, float* __restrict__ acc_num)
{
    __shared__ unsigned s[NSORT];   // exactly 64 KB
    const int b = blockIdx.x;
    const int tid = threadIdx.x;
    int np = num_pos[b];
    int k = NEG_RATIO * np; if (k > AA - 1) k = AA - 1;
    if (k <= 0) return;             // uniform across block

    const float* cn = confneg + (size_t)b * AA;
    const float* cf = conf    + (size_t)b * AA;

    for (int i = tid; i < NSORT; i += 1024)
        s[i] = (i < AA) ? mono_key(cn[i]) : 0xFFFFFFFFu;   // pad sorts last; real keys never equal pad

    // bitonic ascending sort: position k-1 holds the k-th largest conf_neg
    for (unsigned ksz = 2; ksz <= NSORT; ksz <<= 1) {
        for (unsigned j = ksz >> 1; j > 0; j >>= 1) {
            __syncthreads();
            for (unsigned i = tid; i < NSORT; i += 1024) {
                unsigned l = i ^ j;
                if (l > i) {
                    unsigned x = s[i], y = s[l];
                    bool asc = ((i & ksz) == 0);
                    if ((x > y) == asc) { s[i] = y; s[l] = x; }
                }
            }
        }
    }
    __syncthreads();
    const unsigned kth = s[k - 1];   // LDS broadcast
    __syncthreads();                 // everyone has kth; s[] is now reusable

    // stable index-ordered ranges: thread t owns [t*9, t*9+9)
    const int CH = (AA + 1023) / 1024;
    const int lo = tid * CH, hi = (lo + CH < AA) ? lo + CH : AA;
    int cntG = 0, cntE = 0; float sum_gt = 0.f;
    for (int i = lo; i < hi; ++i) {
        unsigned key = mono_key(cn[i]);
        if (key < kth)       { cntG++; sum_gt += cf[i]; }
        else if (key == kth) { cntE++; }
    }

    // inclusive scan of cntE over 1024 threads (Hillis-Steele in s[0..1023])
    s[tid] = (unsigned)cntE;
    for (int off = 1; off < 1024; off <<= 1) {
        __syncthreads();
        unsigned v = (tid >= off) ? s[tid - off] : 0u;
        __syncthreads();
        s[tid] += v;
    }
    __syncthreads();
    const unsigned excl = s[tid] - (unsigned)cntE;

    // reduce total cntG in s[2048..3071]
    unsigned* rg = s + 2048;
    rg[tid] = (unsigned)cntG;
    for (int off = 512; off; off >>= 1) { __syncthreads(); if (tid < off) rg[tid] += rg[tid + off]; }
    __syncthreads();
    const int m = k - (int)rg[0];    // number of ==kth to include (ties by ascending index)

    float sum_eq = 0.f;
    if (m > 0 && cntE > 0) {
        int seen = 0;
        for (int i = lo; i < hi && seen < cntE; ++i) {
            if (mono_key(cn[i]) == kth) {
                if ((int)excl + seen < m) sum_eq += cf[i];
                seen++;
            }
        }
    }

    // reduce the float contribution in s[4096..5119]
    float* rf = (float*)(s + 4096);
    rf[tid] = sum_gt + sum_eq;
    for (int off = 512; off; off >>= 1) { __syncthreads(); if (tid < off) rf[tid] += rf[tid + off]; }
    __syncthreads();
    if (tid == 0) atomicAdd(acc_num, rf[0]);
}

__global__ __launch_bounds__(64) void k_final(
    const int* __restrict__ num_pos, const float* __restrict__ acc_num,
    float* __restrict__ out)
{
    __shared__ int sden[64];
    const int tid = threadIdx.x;
    int np = num_pos[tid];
    sden[tid] = np > 1 ? np : 1;
    __syncthreads();
    for (int off = 32; off; off >>= 1) {
        if (tid < off) sden[tid] += sden[tid + off];
        __syncthreads();
    }
    if (tid == 0) out[0] = acc_num[0] / (float)sden[0];
}

extern "C" void kernel_launch(void* const* d_in, const int* in_sizes, int n_in,
                              void* d_out, int out_size, void* d_ws, size_t ws_size,
                              hipStream_t stream) {
    const float* pred_boxes  = (const float*)d_in[0];
    const float* pred_scores = (const float*)d_in[1];
    const float* gt_boxes    = (const float*)d_in[2];
    const int*   gt_labels   = (const int*)d_in[3];

    float* ws       = (float*)d_ws;
    float* acc_num  = ws;                 // 1 float
    int*   num_pos  = (int*)(ws + 64);    // 64 ints
    float* conf     = ws + 1024;          // BB*AA floats
    float* conf_neg = conf + (size_t)BB * AA;

    // zero header (acc + num_pos); conf arrays are fully overwritten
    hipMemsetAsync(d_ws, 0, 4096, stream);

    dim3 g1((AA + 255) / 256, BB);
    k_match<<<g1, 256, 0, stream>>>(pred_boxes, pred_scores, gt_boxes, gt_labels,
                                    conf, conf_neg, num_pos, acc_num);
    k_hardneg<<<BB, 1024, 0, stream>>>(conf_neg, conf, num_pos, acc_num);
    k_final<<<1, 64, 0, stream>>>(num_pos, acc_num, (float*)d_out);
}

// Round 2
// 303.509 us; speedup vs baseline: 2.6528x; 2.6528x over previous
//
#include <hip/hip_runtime.h>
#include <hip/hip_bf16.h>

#define BB 64
#define AA 8732
#define GG 50
#define CC 81
#define NEG_RATIO 3
#define HW 16          // waves in k_hardneg block
#define HSTRIDE 257    // padded histogram stride (spreads banks)

// ws layout (floats):
//   acc_num        @ 0
//   num_pos[64]    @ 64  (ints)
//   conf[BB*AA]    @ 1024
//   conf_neg[...]  @ 1024 + BB*AA

__device__ __forceinline__ unsigned mono_key(float f) {
    unsigned u = __float_as_uint(f);
    u = (u & 0x80000000u) ? ~u : (u | 0x80000000u);  // ascending float -> ascending uint
    return ~u;                                        // ascending key == descending float
}

__global__ __launch_bounds__(256) void k_match(
    const float* __restrict__ pred_boxes, const float* __restrict__ pred_scores,
    const float* __restrict__ gt_boxes, const int* __restrict__ gt_labels,
    float* __restrict__ conf_out, float* __restrict__ confneg_out,
    int* __restrict__ num_pos, float* __restrict__ acc_num)
{
    __shared__ float4 sgt[GG];
    __shared__ int   slab[GG];
    __shared__ float sscore[64 * CC];   // 20736 B staged score chunk
    __shared__ int   slabel[256];
    __shared__ float cconf[64];
    __shared__ float redf[4];
    __shared__ int   redi[4];

    const int tid = threadIdx.x;
    const int b = blockIdx.y;
    const int abase = blockIdx.x * 256;
    const int a = abase + tid;

    if (tid < GG) {
        const float* gp = gt_boxes + ((size_t)b * GG + tid) * 4;
        sgt[tid] = make_float4(gp[0], gp[1], gp[2], gp[3]);
        slab[tid] = gt_labels[b * GG + tid];
    }
    __syncthreads();

    // ---- phase A: per-thread IoU match ----
    float sl1 = 0.f;
    bool pmask = false;
    if (a < AA) {
        const size_t ai = (size_t)b * AA + a;
        const float4 pb = ((const float4*)pred_boxes)[ai];
        const float area_p = (pb.z - pb.x) * (pb.w - pb.y);
        float best = -1.f; int bidx = 0;
        #pragma unroll 5
        for (int g = 0; g < GG; ++g) {
            float4 gb = sgt[g];
            float iw = fmaxf(fminf(pb.z, gb.z) - fmaxf(pb.x, gb.x), 0.f);
            float ih = fmaxf(fminf(pb.w, gb.w) - fmaxf(pb.y, gb.y), 0.f);
            float inter = iw * ih;
            float area_g = (gb.z - gb.x) * (gb.w - gb.y);
            float uni = fmaxf(area_p + area_g - inter, 1e-6f);
            float iou = inter / uni;
            if (iou > best) { best = iou; bidx = g; }   // strict > keeps FIRST max
        }
        const bool pos = best > 0.5f;
        const int label = pos ? slab[bidx] : 0;
        pmask = label > 0;
        slabel[tid] = label;
        if (pmask) {
            float4 gb = sgt[bidx];
            float d, ad;
            d = pb.x - gb.x; ad = fabsf(d); sl1 += (ad < 1.f) ? 0.5f * d * d : ad - 0.5f;
            d = pb.y - gb.y; ad = fabsf(d); sl1 += (ad < 1.f) ? 0.5f * d * d : ad - 0.5f;
            d = pb.z - gb.z; ad = fabsf(d); sl1 += (ad < 1.f) ? 0.5f * d * d : ad - 0.5f;
            d = pb.w - gb.w; ad = fabsf(d); sl1 += (ad < 1.f) ? 0.5f * d * d : ad - 0.5f;
        }
    } else {
        slabel[tid] = 0;
    }

    // ---- phase B: LDS-staged softmax, 4 lanes per anchor ----
    float myconf = 0.f;
    const int jj = tid >> 2;           // anchor-in-chunk this group computes
    const int q  = tid & 3;            // class-quarter
    const int cstart = q * 21;
    const int cend = (cstart + 21 < CC) ? cstart + 21 : CC;   // q=3 -> 63..80

    for (int c = 0; c < 4; ++c) {
        __syncthreads();
        const int ca = abase + c * 64;
        int na = AA - ca; if (na > 64) na = 64; if (na < 0) na = 0;
        const int nf4 = (na * CC) >> 2;     // always exact (na*81 divisible by 4)
        const float4* src = (const float4*)(pred_scores + ((size_t)b * AA + ca) * CC);
        for (int i = tid; i < nf4; i += 256) ((float4*)sscore)[i] = src[i];
        __syncthreads();
        if (jj < na) {
            const float* srow = sscore + jj * CC;
            float mx = -INFINITY;
            #pragma unroll
            for (int cc = 0; cc < 21; ++cc) {
                int idx = cstart + cc;
                if (idx < cend) mx = fmaxf(mx, srow[idx]);
            }
            mx = fmaxf(mx, __shfl_xor(mx, 1));
            mx = fmaxf(mx, __shfl_xor(mx, 2));
            float sm = 0.f;
            #pragma unroll
            for (int cc = 0; cc < 21; ++cc) {
                int idx = cstart + cc;
                if (idx < cend) sm += __expf(srow[idx] - mx);
            }
            sm += __shfl_xor(sm, 1);
            sm += __shfl_xor(sm, 2);
            if (q == 0) {
                const int lab = slabel[c * 64 + jj];
                cconf[jj] = mx + __logf(sm) - srow[lab];
            }
        }
        __syncthreads();
        if ((tid >> 6) == c && a < AA) myconf = cconf[tid & 63];
    }

    // ---- writes + block reduction ----
    float contrib = 0.f; int ispos = 0;
    if (a < AA) {
        const size_t ai = (size_t)b * AA + a;
        conf_out[ai] = myconf;
        confneg_out[ai] = pmask ? -1.f : myconf;
        if (pmask) { contrib = sl1 + myconf; ispos = 1; }
    }
    #pragma unroll
    for (int off = 32; off; off >>= 1) {
        contrib += __shfl_down(contrib, off);
        ispos   += __shfl_down(ispos, off);
    }
    const int wv = tid >> 6;
    if ((tid & 63) == 0) { redf[wv] = contrib; redi[wv] = ispos; }
    __syncthreads();
    if (tid == 0) {
        float fc = redf[0] + redf[1] + redf[2] + redf[3];
        int   ic = redi[0] + redi[1] + redi[2] + redi[3];
        if (fc != 0.f) atomicAdd(acc_num, fc);
        if (ic)        atomicAdd(&num_pos[b], ic);
    }
}

__global__ __launch_bounds__(1024) void k_hardneg(
    const float* __restrict__ confneg, const float* __restrict__ conf,
    const int* __restrict__ num_pos, float* __restrict__ acc_num)
{
    __shared__ unsigned hist[HW * HSTRIDE];   // 16448 B, per-wave privatized
    __shared__ unsigned scan[1024];
    __shared__ unsigned sel[2];
    __shared__ float    fred[HW];
    __shared__ int      ired[HW];
    __shared__ int      stot;

    const int b = blockIdx.x;
    const int tid = threadIdx.x;
    const int wv = tid >> 6;
    const int np = num_pos[b];
    int k = NEG_RATIO * np; if (k > AA - 1) k = AA - 1;
    if (k <= 0) return;                       // uniform across block

    const float* cn = confneg + (size_t)b * AA;
    const float* cf = conf    + (size_t)b * AA;

    // keys live in registers; contiguous per-thread chunk preserves stable-by-index ties
    const int lo = tid * 9;
    int nk = AA - lo; if (nk > 9) nk = 9; if (nk < 0) nk = 0;
    unsigned keys[9];
    for (int j = 0; j < nk; ++j) keys[j] = mono_key(cn[lo + j]);

    // ---- 4-level radix-256 select: k-th smallest key (1-based rank k) ----
    unsigned prefix = 0;
    unsigned kk = (unsigned)k;
    for (int lev = 0; lev < 4; ++lev) {
        const int shift = 24 - 8 * lev;
        for (int i = tid; i < HW * HSTRIDE; i += 1024) hist[i] = 0;
        __syncthreads();
        for (int j = 0; j < nk; ++j) {
            const unsigned key = keys[j];
            if (lev == 0 || (key >> (shift + 8)) == prefix)
                atomicAdd(&hist[wv * HSTRIDE + ((key >> shift) & 255u)], 1u);
        }
        __syncthreads();
        if (tid < 256) {
            unsigned s = 0;
            #pragma unroll
            for (int w = 0; w < HW; ++w) s += hist[w * HSTRIDE + tid];
            scan[tid] = s;
        }
        __syncthreads();
        for (int off = 1; off < 256; off <<= 1) {     // inclusive scan over 256 bins
            unsigned v = 0;
            if (tid < 256 && tid >= off) v = scan[tid - off];
            __syncthreads();
            if (tid < 256) scan[tid] += v;
            __syncthreads();
        }
        if (tid < 256) {
            const unsigned incl = scan[tid];
            const unsigned excl = tid ? scan[tid - 1] : 0u;
            if (kk > excl && kk <= incl) { sel[0] = (unsigned)tid; sel[1] = kk - excl; }
        }
        __syncthreads();
        prefix = (prefix << 8) | sel[0];
        kk = sel[1];
        __syncthreads();
    }
    const unsigned kth = prefix;

    // ---- stable selection sum: key<kth all in; ties by ascending index ----
    int cntG = 0, cntE = 0; float sum_gt = 0.f;
    for (int j = 0; j < nk; ++j) {
        const unsigned key = keys[j];
        if (key < kth)       { cntG++; sum_gt += cf[lo + j]; }
        else if (key == kth) { cntE++; }
    }

    // inclusive scan of cntE over 1024 threads
    scan[tid] = (unsigned)cntE;
    for (int off = 1; off < 1024; off <<= 1) {
        __syncthreads();
        unsigned v = (tid >= off) ? scan[tid - off] : 0u;
        __syncthreads();
        scan[tid] += v;
    }
    __syncthreads();
    const int excl = (int)scan[tid] - cntE;

    // total cntG
    int g = cntG;
    #pragma unroll
    for (int off = 32; off; off >>= 1) g += __shfl_down(g, off);
    if ((tid & 63) == 0) ired[wv] = g;
    __syncthreads();
    if (tid == 0) {
        int t = 0;
        #pragma unroll
        for (int w = 0; w < HW; ++w) t += ired[w];
        stot = t;
    }
    __syncthreads();
    const int m = k - stot;          // #ties to include, lowest indices first

    float sum_eq = 0.f;
    if (m > 0 && cntE > 0) {
        int seen = 0;
        for (int j = 0; j < nk; ++j) {
            if (keys[j] == kth) {
                if (excl + seen < m) sum_eq += cf[lo + j];
                seen++;
            }
        }
    }

    float contrib = sum_gt + sum_eq;
    #pragma unroll
    for (int off = 32; off; off >>= 1) contrib += __shfl_down(contrib, off);
    if ((tid & 63) == 0) fred[wv] = contrib;
    __syncthreads();
    if (tid == 0) {
        float t = 0.f;
        #pragma unroll
        for (int w = 0; w < HW; ++w) t += fred[w];
        atomicAdd(acc_num, t);
    }
}

__global__ __launch_bounds__(64) void k_final(
    const int* __restrict__ num_pos, const float* __restrict__ acc_num,
    float* __restrict__ out)
{
    __shared__ int sden[64];
    const int tid = threadIdx.x;
    int np = num_pos[tid];
    sden[tid] = np > 1 ? np : 1;
    __syncthreads();
    for (int off = 32; off; off >>= 1) {
        if (tid < off) sden[tid] += sden[tid + off];
        __syncthreads();
    }
    if (tid == 0) out[0] = acc_num[0] / (float)sden[0];
}

extern "C" void kernel_launch(void* const* d_in, const int* in_sizes, int n_in,
                              void* d_out, int out_size, void* d_ws, size_t ws_size,
                              hipStream_t stream) {
    const float* pred_boxes  = (const float*)d_in[0];
    const float* pred_scores = (const float*)d_in[1];
    const float* gt_boxes    = (const float*)d_in[2];
    const int*   gt_labels   = (const int*)d_in[3];

    float* ws       = (float*)d_ws;
    float* acc_num  = ws;                 // 1 float
    int*   num_pos  = (int*)(ws + 64);    // 64 ints
    float* conf     = ws + 1024;          // BB*AA floats
    float* conf_neg = conf + (size_t)BB * AA;

    hipMemsetAsync(d_ws, 0, 4096, stream);

    dim3 g1((AA + 255) / 256, BB);
    k_match<<<g1, 256, 0, stream>>>(pred_boxes, pred_scores, gt_boxes, gt_labels,
                                    conf, conf_neg, num_pos, acc_num);
    k_hardneg<<<BB, 1024, 0, stream>>>(conf_neg, conf, num_pos, acc_num);
    k_final<<<1, 64, 0, stream>>>(num_pos, acc_num, (float*)d_out);
}